// Round 8
// baseline (314.945 us; speedup 1.0000x reference)
//
#include <hip/hip_runtime.h>

#define EPS_F   0.1f
#define INV_EPS 10.0f
#define NB 16
#define NN 512
#define ND 128
#define MAX_ITER 20
#define BPB 16                                        // blocks per batch
#define NEG_INF (-__builtin_inff())
// log(1/512 + 1e-8) computed in fp32 like the reference
#define LOG_MU (-6.2383195f)

#define LD_REL(p)     __hip_atomic_load((p), __ATOMIC_RELAXED, __HIP_MEMORY_SCOPE_AGENT)
#define ST_REL(p, x)  __hip_atomic_store((p), (x), __ATOMIC_RELAXED, __HIP_MEMORY_SCOPE_AGENT)

// Persistent kernel, 256 blocks x 1024 thr (1/CU). bid = 16*t + b -> batch b's
// blocks on XCD b%8 (locality only). ONE barrier per iteration: row sweep (u
// for own 32 rows, LDS-only) -> col-partial sweep over the same L1-hot stripe
// -> publish per-block (m,s) partials (packed u64, relaxed agent atomics,
// double-buffered in ws) -> barrier (per-wave autonomous exit) -> every block
// combines all 16 stripes redundantly -> full v_new in LDS. u, v never touch
// global memory. C written once (GEMM; one __threadfence publishes it), then
// immutable -> plain cached loads. Freeze: write-once slots frozenPub[b][t];
// leader decides in combine(t), everyone applies slot t-1 at top of t+1
// (uniform, deadlock-free; one-iter-late is inert since err ~1e4 >> 1.6).

__device__ __forceinline__ void lse_comb(float& m, float& s, float m2, float s2) {
    float mn = fmaxf(m, m2);
    s = s * __expf(m - mn) + s2 * __expf(m2 - mn);
    m = mn;
}

// ws float layout
#define WS_ERRPART  0       // 512 = 2(buf) x 16(b) x 16(bt)
#define WS_ERRB     512     // 320 = errB[t*16+b], init 1e30
#define WS_COSTPART 832     // 256
#define WS_FPUB     1088    // 320 ints: frozenPub[b*20+t], init 0
#define WS_BARCNT   1408    // 16 x 32 unsigned (128B stride)
#define WS_MSPART   2048    // u64[2][16][16][512] = 2 MB (no init needed)
#define WS_TOTAL    2048    // zeroed region only

__global__ void k_zero(float* __restrict__ ws) {
    int i = blockIdx.x * 256 + threadIdx.x;
    if (i >= WS_TOTAL) return;
    float val = 0.0f;
    if (i >= WS_ERRB && i < WS_ERRB + 320) val = 1e30f;
    ws[i] = val;                                      // zeros ints/unsigneds too
}

__global__ __launch_bounds__(1024, 4) void
k_sink(const float* __restrict__ x, const float* __restrict__ y,
       float* __restrict__ C, float* __restrict__ pi, float* __restrict__ cost,
       float* errPart, float* errB, float* costPart, int* frozenPub,
       unsigned* barCnt, unsigned long long* msPart) {
    __shared__ float As[32][130];
    __shared__ float Bs[32][130];
    __shared__ float xsqS[128];
    __shared__ float ysqS[128];
    __shared__ float vsS[512];                        // full v, block-local
    __shared__ float usS[32];                         // u for own 32 rows
    __shared__ float mH[1024];
    __shared__ float sH[1024];
    __shared__ float partS[16];
    __shared__ int flagS;

    const int tid = threadIdx.x;
    const int bid = blockIdx.x;
    const int b  = bid & 15;
    const int bt = bid >> 4;                          // 0..15 within batch
    unsigned* cnt = barCnt + b * 32;
    unsigned bphase = 0;

    const int w = tid >> 6, l = tid & 63;             // 16 waves

    // Full barrier (GEMM publish / final cost): block-wide wait.
    auto barrier_full = [&](bool flush) {
        ++bphase;
        __syncthreads();                              // per-wave vmcnt drain
        if (tid == 0) {
            if (flush) __threadfence();               // GEMM publish only
            __hip_atomic_fetch_add(cnt, 1u, __ATOMIC_RELAXED, __HIP_MEMORY_SCOPE_AGENT);
            while (LD_REL(cnt) < BPB * bphase)
                __builtin_amdgcn_s_sleep(1);
        }
        __syncthreads();
    };
    // Iteration barrier: per-wave autonomous exit. Each wave's lane 0 polls and
    // the wave proceeds immediately on detection (SIMT reconvergence) — no
    // trailing block sync before the (purely global-read) combine.
    auto barrier_wave = [&]() {
        ++bphase;
        __syncthreads();                              // all waves' stores drained
        if (tid == 0)
            __hip_atomic_fetch_add(cnt, 1u, __ATOMIC_RELAXED, __HIP_MEMORY_SCOPE_AGENT);
        if (l == 0) {
            while (LD_REL(cnt) < BPB * bphase)
                __builtin_amdgcn_s_sleep(1);
        }
    };

    // ================= Phase 0: xsq/ysq + 128x128 GEMM tile =================
    {
        const int gi0 = (bt >> 2) * 128;
        const int gj0 = (bt & 3) * 128;
        for (int r = w; r < 128; r += 16) {
            const float* px = x + ((size_t)(b * NN + gi0 + r)) * ND;
            float a0 = px[l], a1 = px[l + 64];
            float ss = a0 * a0 + a1 * a1;
#pragma unroll
            for (int off = 32; off; off >>= 1) ss += __shfl_xor(ss, off, 64);
            if (l == 0) xsqS[r] = ss;
        }
        for (int r = w; r < 128; r += 16) {
            const float* py = y + ((size_t)(b * NN + gj0 + r)) * ND;
            float a0 = py[l], a1 = py[l + 64];
            float ss = a0 * a0 + a1 * a1;
#pragma unroll
            for (int off = 32; off; off >>= 1) ss += __shfl_xor(ss, off, 64);
            if (l == 0) ysqS[r] = ss;
        }
        const float* xb = x + ((size_t)b * NN + gi0) * ND;
        const float* yb = y + ((size_t)b * NN + gj0) * ND;
        int tx = tid & 31, ty = tid >> 5;             // 32 x 32 thread grid
        float acc[4][4] = {};
        for (int k0 = 0; k0 < ND; k0 += 32) {
            __syncthreads();
            {
                int r  = tid >> 3;                    // 0..127
                int kq = (tid & 7) << 2;              // 0..28
                float4 vx = *(const float4*)(xb + (size_t)r * ND + k0 + kq);
                float4 vy = *(const float4*)(yb + (size_t)r * ND + k0 + kq);
                // stride 130: bank = (8c + 2j + r) % 32 -> exactly 2 lanes/bank (free)
                As[kq + 0][r] = vx.x; As[kq + 1][r] = vx.y;
                As[kq + 2][r] = vx.z; As[kq + 3][r] = vx.w;
                Bs[kq + 0][r] = vy.x; Bs[kq + 1][r] = vy.y;
                Bs[kq + 2][r] = vy.z; Bs[kq + 3][r] = vy.w;
            }
            __syncthreads();
#pragma unroll
            for (int k = 0; k < 32; ++k) {
                float4 av = *(const float4*)&As[k][ty * 4];
                float4 bv = *(const float4*)&Bs[k][tx * 4];
                float ar[4] = {av.x, av.y, av.z, av.w};
                float br[4] = {bv.x, bv.y, bv.z, bv.w};
#pragma unroll
                for (int q = 0; q < 4; ++q)
#pragma unroll
                    for (int p = 0; p < 4; ++p) acc[q][p] += ar[q] * br[p];
            }
        }
#pragma unroll
        for (int q = 0; q < 4; ++q) {
            int il = ty * 4 + q;
            float xq = xsqS[il];
            float* Crow = C + ((size_t)(b * NN + gi0 + il)) * NN + gj0;
            float4 out;
            out.x = xq + ysqS[tx * 4 + 0] - 2.0f * acc[q][0];
            out.y = xq + ysqS[tx * 4 + 1] - 2.0f * acc[q][1];
            out.z = xq + ysqS[tx * 4 + 2] - 2.0f * acc[q][2];
            out.w = xq + ysqS[tx * 4 + 3] - 2.0f * acc[q][3];
            *(float4*)(Crow + tx * 4) = out;
        }
    }
    barrier_full(true);                               // publish C device-wide

    // ================= Sinkhorn iterations (1 barrier each) =================
    if (tid < 512) vsS[tid] = 0.0f;
    if (tid < 32)  usS[tid] = 0.0f;
    if (tid == 0)  flagS = 0;
    __syncthreads();
    int frozenLatch = 0;

    for (int t = 0; t < MAX_ITER; ++t) {
        if (flagS) break;                             // uniform (slot t-2 decision)
        const int buf = t & 1;

        // ---- ROW sweep: u for rows bt*32..+31 (2 rows/wave), LDS-only ----
        float duSum = 0.0f;
#pragma unroll
        for (int rr = 0; rr < 2; ++rr) {
            int i = bt * 32 + w * 2 + rr;
            const float* Crow = C + ((size_t)(b * NN + i)) * NN;
            float4 c0 = *(const float4*)(Crow + 4 * l);
            float4 c1 = *(const float4*)(Crow + 256 + 4 * l);
            float4 v0 = *(const float4*)(vsS + 4 * l);
            float4 v1 = *(const float4*)(vsS + 256 + 4 * l);
            float tv[8] = {(v0.x - c0.x) * INV_EPS, (v0.y - c0.y) * INV_EPS,
                           (v0.z - c0.z) * INV_EPS, (v0.w - c0.w) * INV_EPS,
                           (v1.x - c1.x) * INV_EPS, (v1.y - c1.y) * INV_EPS,
                           (v1.z - c1.z) * INV_EPS, (v1.w - c1.w) * INV_EPS};
            float m = tv[0];
#pragma unroll
            for (int k = 1; k < 8; ++k) m = fmaxf(m, tv[k]);
#pragma unroll
            for (int off = 32; off; off >>= 1)        // global max first: no exps
                m = fmaxf(m, __shfl_xor(m, off, 64)); //   in the reduction
            float s = 0.0f;
#pragma unroll
            for (int k = 0; k < 8; ++k) s += __expf(tv[k] - m);
#pragma unroll
            for (int off = 32; off; off >>= 1) s += __shfl_xor(s, off, 64);
            float un = EPS_F * (LOG_MU - (m + __logf(s)));
            if (l == 0) {
                float uo = usS[w * 2 + rr];
                usS[w * 2 + rr] = un;
                duSum += fabsf(un - uo);
            }
        }
        if (l == 0) partS[w] = duSum;
        __syncthreads();                              // usS + partS complete

        // ---- COL-partial sweep over own (L1-hot) stripe, all 512 cols ----
        {
            int j = tid & 511, h = tid >> 9;          // 2 threads/col, 16 rows each
            const float* Cc = C + ((size_t)(b * NN + bt * 32 + h * 16)) * NN + j;
            float tv[16];
#pragma unroll
            for (int r = 0; r < 16; ++r) tv[r] = Cc[(size_t)r * NN];
#pragma unroll
            for (int r = 0; r < 16; ++r)
                tv[r] = fmaf(tv[r], -INV_EPS, usS[h * 16 + r] * INV_EPS);
            float m = tv[0];
#pragma unroll
            for (int r = 1; r < 16; ++r) m = fmaxf(m, tv[r]);
            float s = 0.0f;
#pragma unroll
            for (int r = 0; r < 16; ++r) s += __expf(tv[r] - m);
            mH[tid] = m;
            sH[tid] = s;
        }
        __syncthreads();
        if (tid < 512) {                              // block partial, packed u64
            float mm = mH[tid], ss = sH[tid];
            lse_comb(mm, ss, mH[tid + 512], sH[tid + 512]);
            unsigned long long up =
                ((unsigned long long)__float_as_uint(ss) << 32) | __float_as_uint(mm);
            ST_REL(msPart + (size_t)buf * 131072 + b * 8192 + bt * 512 + tid, up);
        }
        if (tid == 0) {
            float e = 0.0f;
#pragma unroll
            for (int q = 0; q < 16; ++q) e += partS[q];
            ST_REL(errPart + buf * 256 + b * 16 + bt, e);
        }
        barrier_wave();                               // partials device-visible

        if (tid == 0 && t >= 1)                       // slot t-1: write-once, ordered
            flagS = LD_REL(frozenPub + b * 20 + (t - 1));

        // ---- COMBINE: every block builds full v_new in its own LDS ----
        {
            int j = tid & 511, h = tid >> 9;
            size_t base = (size_t)buf * 131072 + b * 8192 + j;
            unsigned long long up[8];
#pragma unroll
            for (int q = 0; q < 8; ++q)
                up[q] = LD_REL(msPart + base + (size_t)(h * 8 + q) * 512);
            float mq[8], sq[8];
#pragma unroll
            for (int q = 0; q < 8; ++q) {
                mq[q] = __uint_as_float((unsigned)(up[q] & 0xffffffffu));
                sq[q] = __uint_as_float((unsigned)(up[q] >> 32));
            }
            float mm = mq[0];
#pragma unroll
            for (int q = 1; q < 8; ++q) mm = fmaxf(mm, mq[q]);
            float ss = 0.0f;
#pragma unroll
            for (int q = 0; q < 8; ++q) ss += sq[q] * __expf(mq[q] - mm);
            mH[tid] = mm;
            sH[tid] = ss;
        }
        // leader: err bookkeeping + decision(t) -> slot t (wave 15, off hot path)
        if (bt == 0 && w == 15) {
            float e = (l < 16) ? LD_REL(errPart + buf * 256 + b * 16 + l) : 0.0f;
#pragma unroll
            for (int off = 8; off; off >>= 1) e += __shfl_xor(e, off, 64);
            if (l == 0) ST_REL(errB + t * 16 + b, e);
            float g = (l < 16) ? ((l == b) ? e : LD_REL(errB + t * 16 + l)) : 0.0f;
#pragma unroll
            for (int off = 8; off; off >>= 1) g += __shfl_xor(g, off, 64);
            g = __shfl(g, 0, 64);
            frozenLatch |= (g < 0.1f * NB) ? 1 : 0;   // wave-uniform
            if (l == 0) ST_REL(frozenPub + b * 20 + t, frozenLatch);
        }
        __syncthreads();                              // mH/sH + flagS ready
        if (tid < 512) {
            float mm = mH[tid], ss = sH[tid];
            float m2 = mH[tid + 512], s2 = sH[tid + 512];
            float mn = fmaxf(mm, m2);
            ss = ss * __expf(mm - mn) + s2 * __expf(m2 - mn);
            vsS[tid] = EPS_F * (LOG_MU - (mn + __logf(ss)));
        }
        __syncthreads();                              // vsS ready for next sweep
    }

    // ============ PI phase (block-local: usS/vsS/C) — no barrier needed ==========
    float csum = 0.0f;
#pragma unroll
    for (int rr = 0; rr < 2; ++rr) {
        int i = bt * 32 + w * 2 + rr;
        float uu = usS[w * 2 + rr];
        const float* Crow = C + ((size_t)(b * NN + i)) * NN;
        float* prow = pi + ((size_t)(b * NN + i)) * NN;
        float4 c0 = *(const float4*)(Crow + 4 * l);
        float4 c1 = *(const float4*)(Crow + 256 + 4 * l);
        float4 v0 = *(const float4*)(vsS + 4 * l);
        float4 v1 = *(const float4*)(vsS + 256 + 4 * l);
        float4 p0, p1;
        p0.x = __expf((uu + v0.x - c0.x) * INV_EPS);
        p0.y = __expf((uu + v0.y - c0.y) * INV_EPS);
        p0.z = __expf((uu + v0.z - c0.z) * INV_EPS);
        p0.w = __expf((uu + v0.w - c0.w) * INV_EPS);
        p1.x = __expf((uu + v1.x - c1.x) * INV_EPS);
        p1.y = __expf((uu + v1.y - c1.y) * INV_EPS);
        p1.z = __expf((uu + v1.z - c1.z) * INV_EPS);
        p1.w = __expf((uu + v1.w - c1.w) * INV_EPS);
        *(float4*)(prow + 4 * l) = p0;
        *(float4*)(prow + 256 + 4 * l) = p1;
        csum += p0.x * c0.x + p0.y * c0.y + p0.z * c0.z + p0.w * c0.w +
                p1.x * c1.x + p1.y * c1.y + p1.z * c1.z + p1.w * c1.w;
    }
#pragma unroll
    for (int off = 32; off; off >>= 1) csum += __shfl_xor(csum, off, 64);
    if (l == 0) partS[w] = csum;
    __syncthreads();
    if (tid == 0) {
        float s = 0.0f;
#pragma unroll
        for (int q = 0; q < 16; ++q) s += partS[q];
        ST_REL(costPart + b * 16 + bt, s);
    }
    barrier_full(false);                              // cost partials visible
    if (bt == 0 && tid == 0) {
        float s = 0.0f;
        for (int q = 0; q < 16; ++q) s += LD_REL(costPart + b * 16 + q);
        cost[b] = s;                                  // plain store; kernel-end release
    }
}

extern "C" void kernel_launch(void* const* d_in, const int* in_sizes, int n_in,
                              void* d_out, int out_size, void* d_ws, size_t ws_size,
                              hipStream_t stream) {
    const float* x = (const float*)d_in[0];
    const float* y = (const float*)d_in[1];

    // Output layout: cost[16], pi[16*512*512], C[16*512*512]
    float* cost = (float*)d_out;
    float* pi   = cost + 16;
    float* C    = pi + (size_t)NB * NN * NN;

    float* f = (float*)d_ws;
    float* errPart  = f + WS_ERRPART;
    float* errB     = f + WS_ERRB;
    float* costPart = f + WS_COSTPART;
    int*   frozenPub = (int*)(f + WS_FPUB);
    unsigned* barCnt = (unsigned*)(f + WS_BARCNT);
    unsigned long long* msPart = (unsigned long long*)(f + WS_MSPART);

    hipLaunchKernelGGL(k_zero, dim3((WS_TOTAL + 255) / 256), dim3(256), 0, stream, f);

    void* args[] = {(void*)&x, (void*)&y, (void*)&C, (void*)&pi, (void*)&cost,
                    (void*)&errPart, (void*)&errB, (void*)&costPart,
                    (void*)&frozenPub, (void*)&barCnt, (void*)&msPart};
    hipError_t e = hipLaunchCooperativeKernel((const void*)k_sink, dim3(256), dim3(1024),
                                              args, 0, stream);
    if (e != hipSuccess) {
        // Fallback: plain launch. 256 blocks x 1024 thr, 1 block/CU -> co-resident.
        hipLaunchKernelGGL(k_sink, dim3(256), dim3(1024), 0, stream,
                           x, y, C, pi, cost, errPart, errB, costPart,
                           frozenPub, barCnt, msPart);
    }
}

// Round 9
// 244.223 us; speedup vs baseline: 1.2896x; 1.2896x over previous
//
#include <hip/hip_runtime.h>

#define EPS_F   0.1f
#define INV_EPS 10.0f
#define NB 16
#define NN 512
#define ND 128
#define MAX_ITER 20
#define BPB 16                                        // blocks per batch
#define NEG_INF (-__builtin_inff())
// log(1/512 + 1e-8) computed in fp32 like the reference
#define LOG_MU (-6.2383195f)

#define LD_REL(p)     __hip_atomic_load((p), __ATOMIC_RELAXED, __HIP_MEMORY_SCOPE_AGENT)
#define ST_REL(p, x)  __hip_atomic_store((p), (x), __ATOMIC_RELAXED, __HIP_MEMORY_SCOPE_AGENT)

// Persistent kernel, 256 blocks x 1024 thr (1/CU). bid = 16*t + b -> batch b's
// blocks on XCD b%8 (locality heuristic). C written once (GEMM; __threadfence
// in the GEMM barrier emits the L2 writeback that publishes it), immutable
// after; each block then caches its 32-row stripe of C in REGISTERS (row- and
// col-layout fragments, 32 VGPR) -> iteration sweeps do zero C traffic.
// One sync per iteration, flag-based: publish (m,s) col-partials (packed u64,
// relaxed agent atomics, double-buffered in ws) -> __syncthreads (drains each
// wave's vmcnt -> stores acked) -> tid0 stores flags[b][bt]=t+1 -> wave 0
// polls the batch's 16 flags (one 64B line, 16 pollers) -> __syncthreads ->
// combine all 16 stripes redundantly -> v_new in LDS. u,v never touch global.
// Freeze: write-once slots frozenPub[b][t]; leader decides at combine(t),
// everyone applies slot t-1 at top of t+1 (uniform, deadlock-free; the lag is
// inert since err ~1e4 >> 1.6 can never cross 0.1*NB within 20 iters).

__device__ __forceinline__ void lse_comb(float& m, float& s, float m2, float s2) {
    float mn = fmaxf(m, m2);
    s = s * __expf(m - mn) + s2 * __expf(m2 - mn);
    m = mn;
}

// ws float layout
#define WS_ERRPART  0       // 512 = 2(buf) x 16(b) x 16(bt)
#define WS_ERRB     512     // 320 = errB[t*16+b], init 1e30
#define WS_COSTPART 832     // 256
#define WS_FPUB     1088    // 320 ints: frozenPub[b*20+t], init 0
#define WS_FLAGS    1408    // 16 x 32 u32 (128B stride): flags[b*32+bt]
#define WS_BARCNT   1920    // 16 x 32 unsigned (128B stride)
#define WS_MSPART   2560    // u64[2][16][16][512] = 2 MB (no init needed)
#define WS_TOTAL    2560    // zeroed region

__global__ void k_zero(float* __restrict__ ws) {
    int i = blockIdx.x * 256 + threadIdx.x;
    if (i >= WS_TOTAL) return;
    float val = 0.0f;
    if (i >= WS_ERRB && i < WS_ERRB + 320) val = 1e30f;
    ws[i] = val;                                      // zeros ints/unsigneds too
}

__global__ __launch_bounds__(1024, 4) void
k_sink(const float* __restrict__ x, const float* __restrict__ y,
       float* __restrict__ C, float* __restrict__ pi, float* __restrict__ cost,
       float* errPart, float* errB, float* costPart, int* frozenPub,
       unsigned* flags, unsigned* barCnt, unsigned long long* msPart) {
    __shared__ float As[32][132];                     // 132 floats = 528B = 33*16: rows
    __shared__ float Bs[32][132];                     //   16B-aligned -> ds_read_b128 ok
    __shared__ float xsqS[128];
    __shared__ float ysqS[128];
    __shared__ float vsS[512];                        // full v, block-local
    __shared__ float usS[32];                         // u for own 32 rows
    __shared__ float mH[1024];
    __shared__ float sH[1024];
    __shared__ float partS[16];
    __shared__ int flagS;

    const int tid = threadIdx.x;
    const int bid = blockIdx.x;
    const int b  = bid & 15;
    const int bt = bid >> 4;                          // 0..15 within batch
    unsigned* cnt = barCnt + b * 32;
    unsigned* flagsB = flags + b * 32;
    unsigned bphase = 0;

    const int w = tid >> 6, l = tid & 63;             // 16 waves

    // Full barrier (GEMM publish / final cost): single poller, block-wide wait.
    auto barrier_full = [&](bool flush) {
        ++bphase;
        __syncthreads();                              // per-wave vmcnt drain
        if (tid == 0) {
            if (flush) __threadfence();               // GEMM publish only
            __hip_atomic_fetch_add(cnt, 1u, __ATOMIC_RELAXED, __HIP_MEMORY_SCOPE_AGENT);
            while (LD_REL(cnt) < BPB * bphase)
                __builtin_amdgcn_s_sleep(1);
        }
        __syncthreads();
    };

    // ================= Phase 0: xsq/ysq + 128x128 GEMM tile =================
    {
        const int gi0 = (bt >> 2) * 128;
        const int gj0 = (bt & 3) * 128;
        for (int r = w; r < 128; r += 16) {
            const float* px = x + ((size_t)(b * NN + gi0 + r)) * ND;
            float a0 = px[l], a1 = px[l + 64];
            float ss = a0 * a0 + a1 * a1;
#pragma unroll
            for (int off = 32; off; off >>= 1) ss += __shfl_xor(ss, off, 64);
            if (l == 0) xsqS[r] = ss;
        }
        for (int r = w; r < 128; r += 16) {
            const float* py = y + ((size_t)(b * NN + gj0 + r)) * ND;
            float a0 = py[l], a1 = py[l + 64];
            float ss = a0 * a0 + a1 * a1;
#pragma unroll
            for (int off = 32; off; off >>= 1) ss += __shfl_xor(ss, off, 64);
            if (l == 0) ysqS[r] = ss;
        }
        const float* xb = x + ((size_t)b * NN + gi0) * ND;
        const float* yb = y + ((size_t)b * NN + gj0) * ND;
        int tx = tid & 31, ty = tid >> 5;             // 32 x 32 thread grid
        float acc[4][4] = {};
        for (int k0 = 0; k0 < ND; k0 += 32) {
            __syncthreads();
            {
                int r  = tid >> 3;                    // 0..127
                int kq = (tid & 7) << 2;              // 0..28
                float4 vx = *(const float4*)(xb + (size_t)r * ND + k0 + kq);
                float4 vy = *(const float4*)(yb + (size_t)r * ND + k0 + kq);
                As[kq + 0][r] = vx.x; As[kq + 1][r] = vx.y;
                As[kq + 2][r] = vx.z; As[kq + 3][r] = vx.w;
                Bs[kq + 0][r] = vy.x; Bs[kq + 1][r] = vy.y;
                Bs[kq + 2][r] = vy.z; Bs[kq + 3][r] = vy.w;
            }
            __syncthreads();
#pragma unroll
            for (int k = 0; k < 32; ++k) {
                float4 av = *(const float4*)&As[k][ty * 4];
                float4 bv = *(const float4*)&Bs[k][tx * 4];
                float ar[4] = {av.x, av.y, av.z, av.w};
                float br[4] = {bv.x, bv.y, bv.z, bv.w};
#pragma unroll
                for (int q = 0; q < 4; ++q)
#pragma unroll
                    for (int p = 0; p < 4; ++p) acc[q][p] += ar[q] * br[p];
            }
        }
#pragma unroll
        for (int q = 0; q < 4; ++q) {
            int il = ty * 4 + q;
            float xq = xsqS[il];
            float* Crow = C + ((size_t)(b * NN + gi0 + il)) * NN + gj0;
            float4 out;
            out.x = xq + ysqS[tx * 4 + 0] - 2.0f * acc[q][0];
            out.y = xq + ysqS[tx * 4 + 1] - 2.0f * acc[q][1];
            out.z = xq + ysqS[tx * 4 + 2] - 2.0f * acc[q][2];
            out.w = xq + ysqS[tx * 4 + 3] - 2.0f * acc[q][3];
            *(float4*)(Crow + tx * 4) = out;
        }
    }
    barrier_full(true);                               // publish C device-wide

    // ======== One-time C readback into registers (stripe rows bt*32..+31) ========
    // Row layout: wave w owns rows bt*32 + 2w + {0,1}; lane l holds cols
    // 4l..4l+3 and 256+4l..+3 of each (16 VGPR).
    float4 cR[2][2];
#pragma unroll
    for (int rr = 0; rr < 2; ++rr) {
        const float* Crow = C + ((size_t)(b * NN + bt * 32 + w * 2 + rr)) * NN;
        cR[rr][0] = *(const float4*)(Crow + 4 * l);
        cR[rr][1] = *(const float4*)(Crow + 256 + 4 * l);
    }
    // Col layout: thread (j=tid&511, h=tid>>9) holds C[bt*32+h*16+r][j], r=0..15.
    float cC[16];
    {
        int j = tid & 511, h = tid >> 9;
        const float* Cc = C + ((size_t)(b * NN + bt * 32 + h * 16)) * NN + j;
#pragma unroll
        for (int r = 0; r < 16; ++r) cC[r] = Cc[(size_t)r * NN];
    }

    // ================= Sinkhorn iterations (1 flag-sync each) =================
    if (tid < 512) vsS[tid] = 0.0f;
    if (tid == 0)  flagS = 0;
    __syncthreads();
    float uPrev[2] = {0.0f, 0.0f};                    // wave-wide copies of own u
    int frozenLatch = 0;

    for (int t = 0; t < MAX_ITER; ++t) {
        if (flagS) break;                             // uniform (lagged decision)
        const int buf = t & 1;

        // ---- ROW sweep: u for own 2 rows/wave, all from registers + vsS ----
        float duSum = 0.0f, unArr[2];
#pragma unroll
        for (int rr = 0; rr < 2; ++rr) {
            float4 c0 = cR[rr][0], c1 = cR[rr][1];
            float4 v0 = *(const float4*)(vsS + 4 * l);
            float4 v1 = *(const float4*)(vsS + 256 + 4 * l);
            float tv[8] = {(v0.x - c0.x) * INV_EPS, (v0.y - c0.y) * INV_EPS,
                           (v0.z - c0.z) * INV_EPS, (v0.w - c0.w) * INV_EPS,
                           (v1.x - c1.x) * INV_EPS, (v1.y - c1.y) * INV_EPS,
                           (v1.z - c1.z) * INV_EPS, (v1.w - c1.w) * INV_EPS};
            float m = tv[0];
#pragma unroll
            for (int k = 1; k < 8; ++k) m = fmaxf(m, tv[k]);
#pragma unroll
            for (int off = 32; off; off >>= 1)        // max first: no exps in shfl
                m = fmaxf(m, __shfl_xor(m, off, 64));
            float s = 0.0f;
#pragma unroll
            for (int k = 0; k < 8; ++k) s += __expf(tv[k] - m);
#pragma unroll
            for (int off = 32; off; off >>= 1) s += __shfl_xor(s, off, 64);
            float un = EPS_F * (LOG_MU - (m + __logf(s)));
            unArr[rr] = un;
            duSum += fabsf(un - uPrev[rr]);
            uPrev[rr] = un;
        }
        if (l == 0) {
            usS[w * 2 + 0] = unArr[0];
            usS[w * 2 + 1] = unArr[1];
            partS[w] = duSum;
        }
        __syncthreads();                              // usS + partS complete

        // ---- COL-partial sweep from registers (16 rows per thread) ----
        {
            int h = tid >> 9;
            float tvc[16];
#pragma unroll
            for (int r = 0; r < 16; ++r)
                tvc[r] = fmaf(cC[r], -INV_EPS, usS[h * 16 + r] * INV_EPS);
            float m = tvc[0];
#pragma unroll
            for (int r = 1; r < 16; ++r) m = fmaxf(m, tvc[r]);
            float s = 0.0f;
#pragma unroll
            for (int r = 0; r < 16; ++r) s += __expf(tvc[r] - m);
            mH[tid] = m;
            sH[tid] = s;
        }
        __syncthreads();
        if (tid < 512) {                              // block partial, packed u64
            float mm = mH[tid], ss = sH[tid];
            lse_comb(mm, ss, mH[tid + 512], sH[tid + 512]);
            unsigned long long up =
                ((unsigned long long)__float_as_uint(ss) << 32) | __float_as_uint(mm);
            ST_REL(msPart + (size_t)buf * 131072 + b * 8192 + bt * 512 + tid, up);
        }
        if (tid == 0) {
            float e = 0.0f;
#pragma unroll
            for (int q = 0; q < 16; ++q) e += partS[q];
            ST_REL(errPart + buf * 256 + b * 16 + bt, e);
        }
        __syncthreads();                              // all waves' stores acked
        if (tid == 0) ST_REL(flagsB + bt, (unsigned)(t + 1));
        if (w == 0) {                                 // one polling wave per block
            const unsigned tgt = (unsigned)(t + 1);
            for (;;) {
                unsigned fv = (l < 16) ? LD_REL(flagsB + l) : tgt;
                if (__all(fv >= tgt)) break;
                __builtin_amdgcn_s_sleep(1);
            }
        }
        __syncthreads();                              // all partials visible

        if (tid == 0 && t >= 1)                       // slot t-1: write-once, ordered
            flagS = LD_REL(frozenPub + b * 20 + (t - 1));

        // ---- COMBINE: every block builds full v_new in its own LDS ----
        {
            int j = tid & 511, h = tid >> 9;
            size_t base = (size_t)buf * 131072 + b * 8192 + j;
            unsigned long long up[8];
#pragma unroll
            for (int q = 0; q < 8; ++q)
                up[q] = LD_REL(msPart + base + (size_t)(h * 8 + q) * 512);
            float mq[8], sq[8];
#pragma unroll
            for (int q = 0; q < 8; ++q) {
                mq[q] = __uint_as_float((unsigned)(up[q] & 0xffffffffu));
                sq[q] = __uint_as_float((unsigned)(up[q] >> 32));
            }
            float mm = mq[0];
#pragma unroll
            for (int q = 1; q < 8; ++q) mm = fmaxf(mm, mq[q]);
            float ss = 0.0f;
#pragma unroll
            for (int q = 0; q < 8; ++q) ss += sq[q] * __expf(mq[q] - mm);
            mH[tid] = mm;
            sH[tid] = ss;
        }
        // leader: err bookkeeping + decision(t) -> slot t (wave 15, off hot path)
        if (bt == 0 && w == 15) {
            float e = (l < 16) ? LD_REL(errPart + buf * 256 + b * 16 + l) : 0.0f;
#pragma unroll
            for (int off = 8; off; off >>= 1) e += __shfl_xor(e, off, 64);
            if (l == 0) ST_REL(errB + t * 16 + b, e);
            float g = (l < 16) ? ((l == b) ? e : LD_REL(errB + t * 16 + l)) : 0.0f;
#pragma unroll
            for (int off = 8; off; off >>= 1) g += __shfl_xor(g, off, 64);
            g = __shfl(g, 0, 64);
            frozenLatch |= (g < 0.1f * NB) ? 1 : 0;   // wave-uniform
            if (l == 0) ST_REL(frozenPub + b * 20 + t, frozenLatch);
        }
        __syncthreads();                              // mH/sH + flagS ready
        if (tid < 512) {
            float mm = mH[tid], ss = sH[tid];
            float m2 = mH[tid + 512], s2 = sH[tid + 512];
            float mn = fmaxf(mm, m2);
            ss = ss * __expf(mm - mn) + s2 * __expf(m2 - mn);
            vsS[tid] = EPS_F * (LOG_MU - (mn + __logf(ss)));
        }
        __syncthreads();                              // vsS ready for next sweep
    }

    // ============ PI phase (block-local: uPrev/vsS/C-regs) — no barrier ==========
    float csum = 0.0f;
#pragma unroll
    for (int rr = 0; rr < 2; ++rr) {
        int i = bt * 32 + w * 2 + rr;
        float uu = uPrev[rr];
        float* prow = pi + ((size_t)(b * NN + i)) * NN;
        float4 c0 = cR[rr][0], c1 = cR[rr][1];
        float4 v0 = *(const float4*)(vsS + 4 * l);
        float4 v1 = *(const float4*)(vsS + 256 + 4 * l);
        float4 p0, p1;
        p0.x = __expf((uu + v0.x - c0.x) * INV_EPS);
        p0.y = __expf((uu + v0.y - c0.y) * INV_EPS);
        p0.z = __expf((uu + v0.z - c0.z) * INV_EPS);
        p0.w = __expf((uu + v0.w - c0.w) * INV_EPS);
        p1.x = __expf((uu + v1.x - c1.x) * INV_EPS);
        p1.y = __expf((uu + v1.y - c1.y) * INV_EPS);
        p1.z = __expf((uu + v1.z - c1.z) * INV_EPS);
        p1.w = __expf((uu + v1.w - c1.w) * INV_EPS);
        *(float4*)(prow + 4 * l) = p0;
        *(float4*)(prow + 256 + 4 * l) = p1;
        csum += p0.x * c0.x + p0.y * c0.y + p0.z * c0.z + p0.w * c0.w +
                p1.x * c1.x + p1.y * c1.y + p1.z * c1.z + p1.w * c1.w;
    }
#pragma unroll
    for (int off = 32; off; off >>= 1) csum += __shfl_xor(csum, off, 64);
    if (l == 0) partS[w] = csum;
    __syncthreads();
    if (tid == 0) {
        float s = 0.0f;
#pragma unroll
        for (int q = 0; q < 16; ++q) s += partS[q];
        ST_REL(costPart + b * 16 + bt, s);
    }
    barrier_full(false);                              // cost partials visible
    if (bt == 0 && tid == 0) {
        float s = 0.0f;
        for (int q = 0; q < 16; ++q) s += LD_REL(costPart + b * 16 + q);
        cost[b] = s;                                  // plain store; kernel-end release
    }
}

extern "C" void kernel_launch(void* const* d_in, const int* in_sizes, int n_in,
                              void* d_out, int out_size, void* d_ws, size_t ws_size,
                              hipStream_t stream) {
    const float* x = (const float*)d_in[0];
    const float* y = (const float*)d_in[1];

    // Output layout: cost[16], pi[16*512*512], C[16*512*512]
    float* cost = (float*)d_out;
    float* pi   = cost + 16;
    float* C    = pi + (size_t)NB * NN * NN;

    float* f = (float*)d_ws;
    float* errPart  = f + WS_ERRPART;
    float* errB     = f + WS_ERRB;
    float* costPart = f + WS_COSTPART;
    int*   frozenPub = (int*)(f + WS_FPUB);
    unsigned* flags  = (unsigned*)(f + WS_FLAGS);
    unsigned* barCnt = (unsigned*)(f + WS_BARCNT);
    unsigned long long* msPart = (unsigned long long*)(f + WS_MSPART);

    hipLaunchKernelGGL(k_zero, dim3((WS_TOTAL + 255) / 256), dim3(256), 0, stream, f);

    void* args[] = {(void*)&x, (void*)&y, (void*)&C, (void*)&pi, (void*)&cost,
                    (void*)&errPart, (void*)&errB, (void*)&costPart,
                    (void*)&frozenPub, (void*)&flags, (void*)&barCnt, (void*)&msPart};
    hipError_t e = hipLaunchCooperativeKernel((const void*)k_sink, dim3(256), dim3(1024),
                                              args, 0, stream);
    if (e != hipSuccess) {
        // Fallback: plain launch. 256 blocks x 1024 thr, 1 block/CU -> co-resident.
        hipLaunchKernelGGL(k_sink, dim3(256), dim3(1024), 0, stream,
                           x, y, C, pi, cost, errPart, errB, costPart,
                           frozenPub, flags, barCnt, msPart);
    }
}